// Round 4
// baseline (140.373 us; speedup 1.0000x reference)
//
#include <hip/hip_runtime.h>

#define B_ 32
#define D_ 64
#define N_ 254
#define L_ 16
#define H_ 128
#define P_ 96
#define PAIRS (B_*D_)    // 2048
#define XPAIR (N_*L_)    // 4064 floats per (b,d) pair
#define OUT0  (B_*P_*D_) // 196608 floats (output 0)

// ws layout (floats):
#define WS_M    128    // [256]  M = W_enc W_enc^T  ([l1*16+l2])
#define WS_VK   384    // [16]   W_enc @ K,  K = 254*b_enc + colsum(pos)
#define WS_BW   400    // [16]   W_enc @ b_enc
#define WS_BK   416    // [1]    b_enc . K
#define WS_G    432    // [254*16] pos @ W_enc^T  ([n*16+l])
#define WS_PK   4496   // [254]  pos @ K
#define WS_W2T  4752   // [96*128] W2 transposed: W2t[p*128+j] = W2[j*96+p]

typedef float f32x4 __attribute__((ext_vector_type(4)));

// ---- single merged precompute kernel, 256 blocks x 256 threads ----
// blocks 0..253 : G[n]  (no dependencies)
// block 254     : K (colsum), pK, M, vK, bW, bK
// block 255     : W2 transpose into ws
__global__ __launch_bounds__(256) void pre(const float* __restrict__ W_enc,
                                           const float* __restrict__ b_enc,
                                           const float* __restrict__ pos,
                                           const float* __restrict__ W2,
                                           float* __restrict__ ws) {
    int t = threadIdx.x;
    int n = blockIdx.x;

    if (n < N_) {
        __shared__ float pLDS[128], red[256];
        if (t < 128) pLDS[t] = pos[n * H_ + t];
        __syncthreads();
        // G partials: (l = t>>4, c = t&15), 8-wide h-chunk each
        {
            int l = t >> 4, c = t & 15;
            const float* w = W_enc + l * H_ + c * 8;
            const float* p = pLDS + c * 8;
            float s = 0.f;
            #pragma unroll
            for (int i = 0; i < 8; i++) s += p[i] * w[i];
            red[t] = s;
        }
        __syncthreads();
        if (t < 16) {
            float s = 0.f;
            #pragma unroll
            for (int c = 0; c < 16; c++) s += red[t * 16 + c];
            ws[WS_G + n * 16 + t] = s;
        }
    } else if (n == N_) {
        __shared__ float WL[2048], Ks[128], bL[128], red[256];
        // stage W_enc (16x128) into LDS
        for (int i = t; i < 512; i += 256) {
            float4 v = ((const float4*)W_enc)[i];
            float* p = &WL[i * 4];
            p[0] = v.x; p[1] = v.y; p[2] = v.z; p[3] = v.w;
        }
        // colsum(pos): h = t&127, two row-interleaved halves
        {
            int h = t & 127, half = t >> 7;
            float s = 0.f;
            #pragma unroll 4
            for (int r = half; r < N_; r += 2) s += pos[r * H_ + h];
            red[t] = s;
        }
        __syncthreads();
        if (t < 128) {
            float b = b_enc[t];
            bL[t] = b;
            Ks[t] = 254.f * b + red[t] + red[t + 128];
        }
        __syncthreads();
        // pK[n] = pos[n] . K   (row reads hit L1: each 64B line serves 16 h-steps)
        if (t < N_) {
            const float* pr = pos + t * H_;
            float s = 0.f;
            #pragma unroll 8
            for (int h = 0; h < H_; h++) s += pr[h] * Ks[h];
            ws[WS_PK + t] = s;
        }
        // M: entry t = (l1 = t>>4, l2 = t&15)
        {
            int l1 = t >> 4, l2 = t & 15;
            float s = 0.f;
            for (int h = 0; h < H_; h++) s += WL[l1 * H_ + h] * WL[l2 * H_ + h];
            ws[WS_M + t] = s;
        }
        if (t < 16) {
            float s1 = 0.f, s2 = 0.f;
            for (int h = 0; h < H_; h++) {
                float w = WL[t * H_ + h];
                s1 += w * Ks[h];
                s2 += w * bL[h];
            }
            ws[WS_VK + t] = s1;
            ws[WS_BW + t] = s2;
        }
        if (t == 16) {
            float s = 0.f;
            for (int h = 0; h < H_; h++) s += bL[h] * Ks[h];
            ws[WS_BK] = s;
        }
    } else {
        // W2t[p*128+j] = W2[j*96+p] ; coalesced reads, scattered L2 writes (tiny)
        for (int i = t; i < H_ * P_; i += 256) {
            int j = i / P_, p = i - j * P_;
            ws[WS_W2T + p * H_ + j] = W2[i];
        }
    }
}

__global__ __launch_bounds__(256) void mainker(const float* __restrict__ x,
                                               const float* __restrict__ W1,
                                               const float* __restrict__ b1,
                                               const float* __restrict__ b2,
                                               const float* __restrict__ ws,
                                               float* __restrict__ out) {
    __shared__ float xf[N_ * 17 + 16];  // stride-17 padded x tile
    __shared__ float red[256];
    __shared__ float scoreS[N_];
    __shared__ float xsS[16], vS[16], pooledS[16], hS[128];
    __shared__ float s0S, denomS;

    int t  = threadIdx.x;
    int bd = blockIdx.x;   // b*64 + d

    // ---- load x slice: 1016 float4 = 3 full rounds + 248. All 4 loads issued
    //      back-to-back (static unroll); nontemporal keeps the 67MB stream from
    //      evicting G/W1/W2t which every block re-reads. ----
    const f32x4* xv = (const f32x4*)(x + (size_t)bd * XPAIR);
    f32x4*       cv = (f32x4*)(out + OUT0) + (size_t)bd * (XPAIR / 4);

    f32x4 v0 = __builtin_nontemporal_load(xv + t);
    f32x4 v1 = __builtin_nontemporal_load(xv + t + 256);
    f32x4 v2 = __builtin_nontemporal_load(xv + t + 512);
    f32x4 v3 = {0.f, 0.f, 0.f, 0.f};
    bool has3 = (t < 248);
    if (has3) v3 = __builtin_nontemporal_load(xv + t + 768);

    __builtin_nontemporal_store(v0, cv + t);
    __builtin_nontemporal_store(v1, cv + t + 256);
    __builtin_nontemporal_store(v2, cv + t + 512);
    if (has3) __builtin_nontemporal_store(v3, cv + t + 768);

    // unpack to LDS: idx%16 in {0,4,8,12} -> no row crossing
    #define UNPACK(vv, ii) { int idx = (ii) * 4; float* p = &xf[(idx >> 4) * 17 + (idx & 15)]; \
                             p[0] = vv[0]; p[1] = vv[1]; p[2] = vv[2]; p[3] = vv[3]; }
    UNPACK(v0, t); UNPACK(v1, t + 256); UNPACK(v2, t + 512);
    if (has3) UNPACK(v3, t + 768);
    #undef UNPACK
    __syncthreads();

    // ---- xs[l] = sum_n x[n,l] : partials ----
    {
        int l = t & 15, g = t >> 4;
        float s = 0.f;
        for (int n = g; n < N_; n += 16) s += xf[n * 17 + l];
        red[t] = s;
    }
    __syncthreads();

    // ---- wave0 fused: xs final + v = vK + M xs + s0 = bK + xs.bW ----
    if (t < 16) {
        float xsv = 0.f;
        #pragma unroll
        for (int g = 0; g < 16; g++) xsv += red[g * 16 + t];
        xsS[t] = xsv;
        float s = ws[WS_VK + t];
        #pragma unroll
        for (int l2 = 0; l2 < 16; l2++) s += __shfl(xsv, l2) * ws[WS_M + l2 * 16 + t];
        vS[t] = s;
        float s0p = xsv * ws[WS_BW + t];
        #pragma unroll
        for (int off = 8; off; off >>= 1) s0p += __shfl_down(s0p, off);
        if (t == 0) s0S = ws[WS_BK] + s0p;
    }
    __syncthreads();

    // ---- score[n] = s0 + pK[n] + x[n].v + xs.G[n] ----
    if (t < N_) {
        const float* Gn = ws + WS_G + t * 16;
        float s = s0S + ws[WS_PK + t];
        #pragma unroll
        for (int l = 0; l < 16; l++) s += xf[t * 17 + l] * vS[l] + xsS[l] * Gn[l];
        scoreS[t] = s;
    }
    __syncthreads();

    // ---- denom (wave 0) overlapped with pooled partials (all waves) ----
    if (t < 64) {
        float s = 0.f;
        for (int n = t; n < N_; n += 64) s += fabsf(scoreS[n]);
        for (int off = 32; off; off >>= 1) s += __shfl_down(s, off);
        if (t == 0) denomS = s;
    }
    {
        int l = t & 15, g = t >> 4;
        float s = 0.f;
        for (int n = g; n < N_; n += 16) s += xf[n * 17 + l] * scoreS[n];
        red[t] = s;
    }
    __syncthreads();
    if (t < 16) {
        float invd = 1.0f / denomS;
        float s = 0.f;
        #pragma unroll
        for (int g = 0; g < 16; g++) s += red[g * 16 + t];
        pooledS[t] = s * invd;
    }
    __syncthreads();

    // ---- h = leaky_relu(pooled @ W1 + b1, 0.2) ----
    if (t < 128) {
        float s = b1[t];
        #pragma unroll
        for (int l = 0; l < 16; l++) s += pooledS[l] * W1[l * H_ + t];
        hS[t] = s > 0.f ? s : 0.2f * s;
    }
    __syncthreads();

    // ---- out0[b, p, d] = h @ W2 + b2 : vectorized via transposed W2 ----
    if (t < 96) {
        float s = b2[t];
        const float4* w = (const float4*)(ws + WS_W2T + t * H_);
        #pragma unroll
        for (int k = 0; k < 32; k++) {
            float4 wv = w[k];
            s += hS[4 * k] * wv.x + hS[4 * k + 1] * wv.y
               + hS[4 * k + 2] * wv.z + hS[4 * k + 3] * wv.w;
        }
        int b = bd >> 6, d = bd & 63;
        out[b * (P_ * D_) + t * D_ + d] = s;
    }
}

extern "C" void kernel_launch(void* const* d_in, const int* in_sizes, int n_in,
                              void* d_out, int out_size, void* d_ws, size_t ws_size,
                              hipStream_t stream) {
    const float* x     = (const float*)d_in[0];
    const float* W_enc = (const float*)d_in[1];
    const float* b_enc = (const float*)d_in[2];
    const float* W1    = (const float*)d_in[3];
    const float* b1    = (const float*)d_in[4];
    const float* W2    = (const float*)d_in[5];
    const float* b2    = (const float*)d_in[6];
    const float* pos   = (const float*)d_in[7];
    float* ws  = (float*)d_ws;
    float* out = (float*)d_out;

    hipLaunchKernelGGL(pre,     dim3(256),   dim3(256), 0, stream, W_enc, b_enc, pos, W2, ws);
    hipLaunchKernelGGL(mainker, dim3(PAIRS), dim3(256), 0, stream, x, W1, b1, b2, ws, out);
}

// Round 7
// 126.980 us; speedup vs baseline: 1.1055x; 1.1055x over previous
//
#include <hip/hip_runtime.h>

#define B_ 32
#define D_ 64
#define N_ 254
#define L_ 16
#define H_ 128
#define P_ 96
#define PAIRS (B_*D_)    // 2048
#define XPAIR (N_*L_)    // 4064 floats per (b,d) pair
#define OUT0  (B_*P_*D_) // 196608 floats (output 0)

// ws layout (floats):
#define WS_M    128    // [256]  M = W_enc W_enc^T  ([l1*16+l2])
#define WS_VK   384    // [16]   W_enc @ K,  K = 254*b_enc + colsum(pos)
#define WS_BW   400    // [16]   W_enc @ b_enc
#define WS_BK   416    // [1]    b_enc . K
#define WS_G    432    // [254*16] pos @ W_enc^T  ([n*16+l])
#define WS_PK   4496   // [254]  pos @ K

typedef float f32x4 __attribute__((ext_vector_type(4)));

// ---- single merged precompute kernel, 255 blocks x 256 threads ----
// blocks 0..253 : G[n]  (no dependencies)
// block 254     : K (colsum), pK, M, vK, bW, bK
__global__ __launch_bounds__(256) void pre(const float* __restrict__ W_enc,
                                           const float* __restrict__ b_enc,
                                           const float* __restrict__ pos,
                                           float* __restrict__ ws) {
    int t = threadIdx.x;
    int n = blockIdx.x;

    if (n < N_) {
        __shared__ float pLDS[128], red[256];
        if (t < 128) pLDS[t] = pos[n * H_ + t];
        __syncthreads();
        // G partials: (l = t>>4, c = t&15), 8-wide h-chunk each
        {
            int l = t >> 4, c = t & 15;
            const float* w = W_enc + l * H_ + c * 8;
            const float* p = pLDS + c * 8;
            float s = 0.f;
            #pragma unroll
            for (int i = 0; i < 8; i++) s += p[i] * w[i];
            red[t] = s;
        }
        __syncthreads();
        if (t < 16) {
            float s = 0.f;
            #pragma unroll
            for (int c = 0; c < 16; c++) s += red[t * 16 + c];
            ws[WS_G + n * 16 + t] = s;
        }
    } else {
        __shared__ float WL[2048], Ks[128], bL[128], red[256];
        // stage W_enc (16x128) into LDS
        for (int i = t; i < 512; i += 256) {
            float4 v = ((const float4*)W_enc)[i];
            float* p = &WL[i * 4];
            p[0] = v.x; p[1] = v.y; p[2] = v.z; p[3] = v.w;
        }
        // colsum(pos): h = t&127, two row-interleaved halves
        {
            int h = t & 127, half = t >> 7;
            float s = 0.f;
            #pragma unroll 4
            for (int r = half; r < N_; r += 2) s += pos[r * H_ + h];
            red[t] = s;
        }
        __syncthreads();
        if (t < 128) {
            float b = b_enc[t];
            bL[t] = b;
            Ks[t] = 254.f * b + red[t] + red[t + 128];
        }
        __syncthreads();
        // pK[n] = pos[n] . K   (row reads; L1 serves 16 h-steps per 64B line)
        if (t < N_) {
            const float* pr = pos + t * H_;
            float s = 0.f;
            #pragma unroll 8
            for (int h = 0; h < H_; h++) s += pr[h] * Ks[h];
            ws[WS_PK + t] = s;
        }
        // M: entry t = (l1 = t>>4, l2 = t&15)
        {
            int l1 = t >> 4, l2 = t & 15;
            float s = 0.f;
            for (int h = 0; h < H_; h++) s += WL[l1 * H_ + h] * WL[l2 * H_ + h];
            ws[WS_M + t] = s;
        }
        if (t < 16) {
            float s1 = 0.f, s2 = 0.f;
            for (int h = 0; h < H_; h++) {
                float w = WL[t * H_ + h];
                s1 += w * Ks[h];
                s2 += w * bL[h];
            }
            ws[WS_VK + t] = s1;
            ws[WS_BW + t] = s2;
        }
        if (t == 16) {
            float s = 0.f;
            for (int h = 0; h < H_; h++) s += bL[h] * Ks[h];
            ws[WS_BK] = s;
        }
    }
}

__global__ __launch_bounds__(256) void mainker(const float* __restrict__ x,
                                               const float* __restrict__ W1,
                                               const float* __restrict__ b1,
                                               const float* __restrict__ W2,
                                               const float* __restrict__ b2,
                                               const float* __restrict__ ws,
                                               float* __restrict__ out) {
    __shared__ float xf[N_ * 17 + 16];  // stride-17 padded x tile
    __shared__ float red[256];
    __shared__ float scoreS[N_];
    __shared__ float xsS[16], vS[16], pooledS[16], hS[128];
    __shared__ float s0S, denomS;

    int t  = threadIdx.x;
    int bd = blockIdx.x;   // b*64 + d

    // ---- load x slice: 1016 float4 = 3 full rounds + 248, statically unrolled
    //      so all 4 independent loads issue back-to-back (plain loads/stores;
    //      nt hints regressed in R4). ----
    const f32x4* xv = (const f32x4*)(x + (size_t)bd * XPAIR);
    f32x4*       cv = (f32x4*)(out + OUT0) + (size_t)bd * (XPAIR / 4);

    f32x4 v0 = xv[t];
    f32x4 v1 = xv[t + 256];
    f32x4 v2 = xv[t + 512];
    f32x4 v3 = {0.f, 0.f, 0.f, 0.f};
    bool has3 = (t < 248);
    if (has3) v3 = xv[t + 768];

    cv[t]       = v0;
    cv[t + 256] = v1;
    cv[t + 512] = v2;
    if (has3) cv[t + 768] = v3;

    // unpack to LDS: idx%16 in {0,4,8,12} -> no row crossing
    #define UNPACK(vv, ii) { int idx = (ii) * 4; float* p = &xf[(idx >> 4) * 17 + (idx & 15)]; \
                             p[0] = vv[0]; p[1] = vv[1]; p[2] = vv[2]; p[3] = vv[3]; }
    UNPACK(v0, t); UNPACK(v1, t + 256); UNPACK(v2, t + 512);
    if (has3) UNPACK(v3, t + 768);
    #undef UNPACK
    __syncthreads();

    // ---- xs[l] = sum_n x[n,l] : partials ----
    {
        int l = t & 15, g = t >> 4;
        float s = 0.f;
        for (int n = g; n < N_; n += 16) s += xf[n * 17 + l];
        red[t] = s;
    }
    __syncthreads();

    // ---- wave0 fused: xs final + v = vK + M xs + s0 = bK + xs.bW ----
    if (t < 16) {
        float xsv = 0.f;
        #pragma unroll
        for (int g = 0; g < 16; g++) xsv += red[g * 16 + t];
        xsS[t] = xsv;
        float s = ws[WS_VK + t];
        #pragma unroll
        for (int l2 = 0; l2 < 16; l2++) s += __shfl(xsv, l2) * ws[WS_M + l2 * 16 + t];
        vS[t] = s;
        float s0p = xsv * ws[WS_BW + t];
        #pragma unroll
        for (int off = 8; off; off >>= 1) s0p += __shfl_down(s0p, off);
        if (t == 0) s0S = ws[WS_BK] + s0p;
    }
    __syncthreads();

    // ---- score[n] = s0 + pK[n] + x[n].v + xs.G[n] ----
    if (t < N_) {
        const float* Gn = ws + WS_G + t * 16;
        float s = s0S + ws[WS_PK + t];
        #pragma unroll
        for (int l = 0; l < 16; l++) s += xf[t * 17 + l] * vS[l] + xsS[l] * Gn[l];
        scoreS[t] = s;
    }
    __syncthreads();

    // ---- denom (wave 0) overlapped with pooled partials (all waves) ----
    if (t < 64) {
        float s = 0.f;
        for (int n = t; n < N_; n += 64) s += fabsf(scoreS[n]);
        for (int off = 32; off; off >>= 1) s += __shfl_down(s, off);
        if (t == 0) denomS = s;
    }
    {
        int l = t & 15, g = t >> 4;
        float s = 0.f;
        for (int n = g; n < N_; n += 16) s += xf[n * 17 + l] * scoreS[n];
        red[t] = s;
    }
    __syncthreads();
    if (t < 16) {
        float invd = 1.0f / denomS;
        float s = 0.f;
        #pragma unroll
        for (int g = 0; g < 16; g++) s += red[g * 16 + t];
        pooledS[t] = s * invd;
    }
    __syncthreads();

    // ---- h = leaky_relu(pooled @ W1 + b1, 0.2) ----
    if (t < 128) {
        float s = b1[t];
        #pragma unroll
        for (int l = 0; l < 16; l++) s += pooledS[l] * W1[l * H_ + t];
        hS[t] = s > 0.f ? s : 0.2f * s;
    }
    __syncthreads();

    // ---- out0[b, p, d] = h @ W2 + b2 : coalesced scalar W2 (lane-consecutive) ----
    if (t < 96) {
        float s = b2[t];
        for (int j = 0; j < 128; j++) s += hS[j] * W2[j * P_ + t];
        int b = bd >> 6, d = bd & 63;
        out[b * (P_ * D_) + t * D_ + d] = s;
    }
}

extern "C" void kernel_launch(void* const* d_in, const int* in_sizes, int n_in,
                              void* d_out, int out_size, void* d_ws, size_t ws_size,
                              hipStream_t stream) {
    const float* x     = (const float*)d_in[0];
    const float* W_enc = (const float*)d_in[1];
    const float* b_enc = (const float*)d_in[2];
    const float* W1    = (const float*)d_in[3];
    const float* b1    = (const float*)d_in[4];
    const float* W2    = (const float*)d_in[5];
    const float* b2    = (const float*)d_in[6];
    const float* pos   = (const float*)d_in[7];
    float* ws  = (float*)d_ws;
    float* out = (float*)d_out;

    hipLaunchKernelGGL(pre,     dim3(255),   dim3(256), 0, stream, W_enc, b_enc, pos, ws);
    hipLaunchKernelGGL(mainker, dim3(PAIRS), dim3(256), 0, stream, x, W1, b1, W2, b2, ws, out);
}

// Round 8
// 119.988 us; speedup vs baseline: 1.1699x; 1.0583x over previous
//
#include <hip/hip_runtime.h>

#define B_ 32
#define D_ 64
#define N_ 254
#define L_ 16
#define H_ 128
#define P_ 96
#define PAIRS (B_*D_)    // 2048
#define XPAIR (N_*L_)    // 4064 floats per (b,d) pair
#define OUT0  (B_*P_*D_) // 196608 floats (output 0)

// ws layout (floats):
#define WS_M    128    // [256]  M = W_enc W_enc^T  ([l1*16+l2])
#define WS_VK   384    // [16]   W_enc @ K,  K = 254*b_enc + colsum(pos)
#define WS_BW   400    // [16]   W_enc @ b_enc
#define WS_BK   416    // [1]    b_enc . K
#define WS_G    432    // [254*16] pos @ W_enc^T  ([n*16+l])
#define WS_PK   4496   // [254]  pos @ K
#define WS_KP   4752   // [16*128] partial column sums of pos

typedef float f32x4 __attribute__((ext_vector_type(4)));

// ---- stage 1: partial column sums of pos (254 x 128), coalesced ----
__global__ __launch_bounds__(256) void preK(const float* __restrict__ pos,
                                            float* __restrict__ ws) {
    __shared__ float red[256];
    int t = threadIdx.x;
    int h = t & 127, j = t >> 7;          // j in {0,1}
    int n0 = blockIdx.x * 16;             // 16 blocks x 16 rows (last: 14)
    float acc = 0.f;
    #pragma unroll
    for (int r = 0; r < 8; r++) {
        int n = n0 + j + 2 * r;
        if (n < N_) acc += pos[n * H_ + h];
    }
    red[t] = acc;
    __syncthreads();
    if (t < 128) ws[WS_KP + blockIdx.x * 128 + t] = red[t] + red[t + 128];
}

// ---- stage 2: G,pK (blocks 0..253) + M,vK,bW,bK (block 254) ----
__global__ __launch_bounds__(128) void pre2b(const float* __restrict__ W_enc,
                                             const float* __restrict__ b_enc,
                                             const float* __restrict__ pos,
                                             float* __restrict__ ws) {
    __shared__ float Ks[128], bL[128], pLDS[128], red[128], red2[128];
    __shared__ float WL[2048];
    int t = threadIdx.x;                  // 128 threads
    int n = blockIdx.x;                   // 0..254

    // rebuild K locally (L2-hot partials): K[h] = 254*b_enc[h] + sum_g part
    {
        float b = b_enc[t];
        float s = 254.f * b;
        #pragma unroll
        for (int g = 0; g < 16; g++) s += ws[WS_KP + g * 128 + t];
        Ks[t] = s;
        bL[t] = b;
    }

    if (n < N_) {
        pLDS[t] = pos[n * H_ + t];
        __syncthreads();
        // G partials: t -> (l = t>>3, c = t&7), 16-wide h-chunk each
        {
            int l = t >> 3, c = t & 7;
            const float* w = W_enc + l * H_ + c * 16;
            const float* p = pLDS + c * 16;
            float s = 0.f;
            #pragma unroll
            for (int i = 0; i < 16; i++) s += p[i] * w[i];
            red[t] = s;
            red2[t] = pLDS[t] * Ks[t];
        }
        __syncthreads();
        if (t < 16) {                     // G final
            float s = 0.f;
            #pragma unroll
            for (int c = 0; c < 8; c++) s += red[t * 8 + c];
            ws[WS_G + n * 16 + t] = s;
        }
        if (t >= 64) {                    // pK final (wave 1)
            int lane = t - 64;
            float s = red2[lane] + red2[lane + 64];
            for (int off = 32; off; off >>= 1) s += __shfl_down(s, off);
            if (lane == 0) ws[WS_PK + n] = s;
        }
    } else {
        // block 254: stage W_enc (16x128) into LDS, then tiny dots
        for (int i = t; i < 512; i += 128) {
            float4 v = ((const float4*)W_enc)[i];
            float* p = &WL[i * 4];
            p[0] = v.x; p[1] = v.y; p[2] = v.z; p[3] = v.w;
        }
        __syncthreads();
        #pragma unroll
        for (int e0 = 0; e0 < 2; e0++) {  // M: 256 entries / 128 threads
            int e = e0 * 128 + t;
            int l1 = e >> 4, l2 = e & 15;
            float s = 0.f;
            for (int h = 0; h < H_; h++) s += WL[l1 * H_ + h] * WL[l2 * H_ + h];
            ws[WS_M + e] = s;
        }
        if (t < 16) {
            float s1 = 0.f, s2 = 0.f;
            for (int h = 0; h < H_; h++) {
                float w = WL[t * H_ + h];
                s1 += w * Ks[h];
                s2 += w * bL[h];
            }
            ws[WS_VK + t] = s1;
            ws[WS_BW + t] = s2;
        }
        if (t == 16) {
            float s = 0.f;
            for (int h = 0; h < H_; h++) s += bL[h] * Ks[h];
            ws[WS_BK] = s;
        }
    }
}

__global__ __launch_bounds__(256) void mainker(const float* __restrict__ x,
                                               const float* __restrict__ W1,
                                               const float* __restrict__ b1,
                                               const float* __restrict__ W2,
                                               const float* __restrict__ b2,
                                               const float* __restrict__ ws,
                                               float* __restrict__ out) {
    __shared__ float xf[N_ * 17 + 16];  // stride-17 padded x tile
    __shared__ float red[256];
    __shared__ float scoreS[N_];
    __shared__ float xsS[16], vS[16], pooledS[16], hS[128];
    __shared__ float s0S, denomS;

    int t  = threadIdx.x;
    int bd = blockIdx.x;   // b*64 + d

    // ---- load x slice: 1016 float4 = 3 full rounds + 248, statically unrolled
    //      so all 4 independent loads issue back-to-back ----
    const f32x4* xv = (const f32x4*)(x + (size_t)bd * XPAIR);
    f32x4*       cv = (f32x4*)(out + OUT0) + (size_t)bd * (XPAIR / 4);

    f32x4 v0 = xv[t];
    f32x4 v1 = xv[t + 256];
    f32x4 v2 = xv[t + 512];
    f32x4 v3 = {0.f, 0.f, 0.f, 0.f};
    bool has3 = (t < 248);
    if (has3) v3 = xv[t + 768];

    cv[t]       = v0;
    cv[t + 256] = v1;
    cv[t + 512] = v2;
    if (has3) cv[t + 768] = v3;

    // unpack to LDS: idx%16 in {0,4,8,12} -> no row crossing
    #define UNPACK(vv, ii) { int idx = (ii) * 4; float* p = &xf[(idx >> 4) * 17 + (idx & 15)]; \
                             p[0] = vv[0]; p[1] = vv[1]; p[2] = vv[2]; p[3] = vv[3]; }
    UNPACK(v0, t); UNPACK(v1, t + 256); UNPACK(v2, t + 512);
    if (has3) UNPACK(v3, t + 768);
    #undef UNPACK
    __syncthreads();

    // ---- xs[l] = sum_n x[n,l] : partials ----
    {
        int l = t & 15, g = t >> 4;
        float s = 0.f;
        for (int n = g; n < N_; n += 16) s += xf[n * 17 + l];
        red[t] = s;
    }
    __syncthreads();

    // ---- wave0 fused: xs final + v = vK + M xs + s0 = bK + xs.bW ----
    if (t < 16) {
        float xsv = 0.f;
        #pragma unroll
        for (int g = 0; g < 16; g++) xsv += red[g * 16 + t];
        xsS[t] = xsv;
        float s = ws[WS_VK + t];
        #pragma unroll
        for (int l2 = 0; l2 < 16; l2++) s += __shfl(xsv, l2) * ws[WS_M + l2 * 16 + t];
        vS[t] = s;
        float s0p = xsv * ws[WS_BW + t];
        #pragma unroll
        for (int off = 8; off; off >>= 1) s0p += __shfl_down(s0p, off);
        if (t == 0) s0S = ws[WS_BK] + s0p;
    }
    __syncthreads();

    // ---- score[n] = s0 + pK[n] + x[n].v + xs.G[n] ----
    if (t < N_) {
        const float* Gn = ws + WS_G + t * 16;
        float s = s0S + ws[WS_PK + t];
        #pragma unroll
        for (int l = 0; l < 16; l++) s += xf[t * 17 + l] * vS[l] + xsS[l] * Gn[l];
        scoreS[t] = s;
    }
    __syncthreads();

    // ---- denom (wave 0) overlapped with pooled partials (all waves) ----
    if (t < 64) {
        float s = 0.f;
        for (int n = t; n < N_; n += 64) s += fabsf(scoreS[n]);
        for (int off = 32; off; off >>= 1) s += __shfl_down(s, off);
        if (t == 0) denomS = s;
    }
    {
        int l = t & 15, g = t >> 4;
        float s = 0.f;
        for (int n = g; n < N_; n += 16) s += xf[n * 17 + l] * scoreS[n];
        red[t] = s;
    }
    __syncthreads();
    if (t < 16) {
        float invd = 1.0f / denomS;
        float s = 0.f;
        #pragma unroll
        for (int g = 0; g < 16; g++) s += red[g * 16 + t];
        pooledS[t] = s * invd;
    }
    __syncthreads();

    // ---- h = leaky_relu(pooled @ W1 + b1, 0.2) ----
    if (t < 128) {
        float s = b1[t];
        #pragma unroll
        for (int l = 0; l < 16; l++) s += pooledS[l] * W1[l * H_ + t];
        hS[t] = s > 0.f ? s : 0.2f * s;
    }
    __syncthreads();

    // ---- out0[b, p, d] = h @ W2 + b2 : coalesced scalar W2 (lane-consecutive) ----
    if (t < 96) {
        float s = b2[t];
        for (int j = 0; j < 128; j++) s += hS[j] * W2[j * P_ + t];
        int b = bd >> 6, d = bd & 63;
        out[b * (P_ * D_) + t * D_ + d] = s;
    }
}

extern "C" void kernel_launch(void* const* d_in, const int* in_sizes, int n_in,
                              void* d_out, int out_size, void* d_ws, size_t ws_size,
                              hipStream_t stream) {
    const float* x     = (const float*)d_in[0];
    const float* W_enc = (const float*)d_in[1];
    const float* b_enc = (const float*)d_in[2];
    const float* W1    = (const float*)d_in[3];
    const float* b1    = (const float*)d_in[4];
    const float* W2    = (const float*)d_in[5];
    const float* b2    = (const float*)d_in[6];
    const float* pos   = (const float*)d_in[7];
    float* ws  = (float*)d_ws;
    float* out = (float*)d_out;

    hipLaunchKernelGGL(preK,   dim3(16),    dim3(256), 0, stream, pos, ws);
    hipLaunchKernelGGL(pre2b,  dim3(255),   dim3(128), 0, stream, W_enc, b_enc, pos, ws);
    hipLaunchKernelGGL(mainker, dim3(PAIRS), dim3(256), 0, stream, x, W1, b1, W2, b2, ws, out);
}

// Round 13
// 119.522 us; speedup vs baseline: 1.1745x; 1.0039x over previous
//
#include <hip/hip_runtime.h>

#define B_ 32
#define D_ 64
#define N_ 254
#define L_ 16
#define H_ 128
#define P_ 96
#define PAIRS (B_*D_)    // 2048
#define XPAIR (N_*L_)    // 4064 floats per (b,d) pair
#define OUT0  (B_*P_*D_) // 196608 floats (output 0)

// ws layout (floats):
#define WS_M    128    // [256]  M = W_enc W_enc^T  ([l1*16+l2])
#define WS_VK   384    // [16]   W_enc @ K,  K = 254*b_enc + colsum(pos)
#define WS_BW   400    // [16]   W_enc @ b_enc
#define WS_BK   416    // [1]    b_enc . K
#define WS_G    432    // [254*16] pos @ W_enc^T  ([n*16+l])
#define WS_PK   4496   // [254]  pos @ K
#define WS_KP   4752   // [16*128] partial column sums of pos

typedef float f32x4 __attribute__((ext_vector_type(4)));

// ---- stage 1: partial column sums of pos (254 x 128), coalesced ----
__global__ __launch_bounds__(256) void preK(const float* __restrict__ pos,
                                            float* __restrict__ ws) {
    __shared__ float red[256];
    int t = threadIdx.x;
    int h = t & 127, j = t >> 7;          // j in {0,1}
    int n0 = blockIdx.x * 16;             // 16 blocks x 16 rows (last: 14)
    float acc = 0.f;
    #pragma unroll
    for (int r = 0; r < 8; r++) {
        int n = n0 + j + 2 * r;
        if (n < N_) acc += pos[n * H_ + h];
    }
    red[t] = acc;
    __syncthreads();
    if (t < 128) ws[WS_KP + blockIdx.x * 128 + t] = red[t] + red[t + 128];
}

// ---- stage 2: G,pK (blocks 0..253) + M,vK,bW,bK (block 254) ----
__global__ __launch_bounds__(128) void pre2b(const float* __restrict__ W_enc,
                                             const float* __restrict__ b_enc,
                                             const float* __restrict__ pos,
                                             float* __restrict__ ws) {
    __shared__ float Ks[128], bL[128], pLDS[128], red[128], red2[128];
    __shared__ float WL[2048];
    int t = threadIdx.x;                  // 128 threads
    int n = blockIdx.x;                   // 0..254

    // rebuild K locally (L2-hot partials): K[h] = 254*b_enc[h] + sum_g part
    {
        float b = b_enc[t];
        float s = 254.f * b;
        #pragma unroll
        for (int g = 0; g < 16; g++) s += ws[WS_KP + g * 128 + t];
        Ks[t] = s;
        bL[t] = b;
    }

    if (n < N_) {
        pLDS[t] = pos[n * H_ + t];
        __syncthreads();
        // G partials: t -> (l = t>>3, c = t&7), 16-wide h-chunk each
        {
            int l = t >> 3, c = t & 7;
            const float* w = W_enc + l * H_ + c * 16;
            const float* p = pLDS + c * 16;
            float s = 0.f;
            #pragma unroll
            for (int i = 0; i < 16; i++) s += p[i] * w[i];
            red[t] = s;
            red2[t] = pLDS[t] * Ks[t];
        }
        __syncthreads();
        if (t < 16) {                     // G final
            float s = 0.f;
            #pragma unroll
            for (int c = 0; c < 8; c++) s += red[t * 8 + c];
            ws[WS_G + n * 16 + t] = s;
        }
        if (t >= 64) {                    // pK final (wave 1)
            int lane = t - 64;
            float s = red2[lane] + red2[lane + 64];
            for (int off = 32; off; off >>= 1) s += __shfl_down(s, off);
            if (lane == 0) ws[WS_PK + n] = s;
        }
    } else {
        // block 254: stage W_enc (16x128) into LDS, then tiny dots
        for (int i = t; i < 512; i += 128) {
            float4 v = ((const float4*)W_enc)[i];
            float* p = &WL[i * 4];
            p[0] = v.x; p[1] = v.y; p[2] = v.z; p[3] = v.w;
        }
        __syncthreads();
        #pragma unroll
        for (int e0 = 0; e0 < 2; e0++) {  // M: 256 entries / 128 threads
            int e = e0 * 128 + t;
            int l1 = e >> 4, l2 = e & 15;
            float s = 0.f;
            for (int h = 0; h < H_; h++) s += WL[l1 * H_ + h] * WL[l2 * H_ + h];
            ws[WS_M + e] = s;
        }
        if (t < 16) {
            float s1 = 0.f, s2 = 0.f;
            for (int h = 0; h < H_; h++) {
                float w = WL[t * H_ + h];
                s1 += w * Ks[h];
                s2 += w * bL[h];
            }
            ws[WS_VK + t] = s1;
            ws[WS_BW + t] = s2;
        }
        if (t == 16) {
            float s = 0.f;
            for (int h = 0; h < H_; h++) s += bL[h] * Ks[h];
            ws[WS_BK] = s;
        }
    }
}

// ---- main: x kept entirely in registers; thread t owns quad (t&3) of rows
//      {t>>2, t>>2+64, t>>2+128, t>>2+192}. No x tile in LDS. ----
__global__ __launch_bounds__(256) void mainker(const float* __restrict__ x,
                                               const float* __restrict__ W1,
                                               const float* __restrict__ b1,
                                               const float* __restrict__ W2,
                                               const float* __restrict__ b2,
                                               const float* __restrict__ ws,
                                               float* __restrict__ out) {
    __shared__ f32x4 red4[256];          // 4 KB reduction scratch
    __shared__ float scoreS[256];        // padded to 256
    __shared__ float xsS[16], vS[16], pooledS[16], hS[128];
    __shared__ float s0S, denomS;

    int t  = threadIdx.x;
    int bd = blockIdx.x;                 // b*64 + d
    int q  = t & 3, r0 = t >> 2;         // quad, base row

    const f32x4* xv = (const f32x4*)(x + (size_t)bd * XPAIR);
    f32x4*       cv = (f32x4*)(out + OUT0) + (size_t)bd * (XPAIR / 4);

    f32x4 v0 = xv[t];
    f32x4 v1 = xv[t + 256];
    f32x4 v2 = xv[t + 512];
    f32x4 v3 = {0.f, 0.f, 0.f, 0.f};
    bool has3 = (t < 248);               // rows 254/255 don't exist
    if (has3) v3 = xv[t + 768];

    cv[t]       = v0;
    cv[t + 256] = v1;
    cv[t + 512] = v2;
    if (has3) cv[t + 768] = v3;

    // ---- xs partials: one float4 per thread ----
    red4[t] = v0 + v1 + v2 + v3;
    __syncthreads();
    if (t < 64) red4[t] = red4[t] + red4[t + 64] + red4[t + 128] + red4[t + 192];
    __syncthreads();

    // ---- wave0: xs final + v = vK + M xs + s0 = bK + xs.bW ----
    if (t < 16) {
        float xsv = 0.f;
        #pragma unroll
        for (int m = 0; m < 16; m++) xsv += red4[m * 4 + (t >> 2)][t & 3];
        xsS[t] = xsv;
        float s = ws[WS_VK + t];
        #pragma unroll
        for (int l2 = 0; l2 < 16; l2++) s += __shfl(xsv, l2) * ws[WS_M + l2 * 16 + t];
        vS[t] = s;
        float s0p = xsv * ws[WS_BW + t];
        #pragma unroll
        for (int off = 8; off; off >>= 1) s0p += __shfl_down(s0p, off);
        if (t == 0) s0S = ws[WS_BK] + s0p;
    }
    __syncthreads();

    // ---- score[n] by 4-lane groups from registers; G reads coalesced float4 ----
    {
        float vq0 = vS[4*q], vq1 = vS[4*q+1], vq2 = vS[4*q+2], vq3 = vS[4*q+3];
        float xq0 = xsS[4*q], xq1 = xsS[4*q+1], xq2 = xsS[4*q+2], xq3 = xsS[4*q+3];
        #pragma unroll
        for (int k = 0; k < 4; k++) {
            if (k < 3 || has3) {
                int rk = r0 + 64 * k;
                f32x4 xk = (k == 0) ? v0 : (k == 1) ? v1 : (k == 2) ? v2 : v3;
                f32x4 g  = *(const f32x4*)(ws + WS_G + rk * 16 + 4 * q);
                float s = xk[0]*vq0 + xk[1]*vq1 + xk[2]*vq2 + xk[3]*vq3
                        + xq0*g[0] + xq1*g[1] + xq2*g[2] + xq3*g[3];
                s += __shfl_xor(s, 1);
                s += __shfl_xor(s, 2);
                if (q == 0) scoreS[rk] = s + s0S + ws[WS_PK + rk];
            }
        }
    }
    __syncthreads();

    // ---- denom (wave 0) overlapped with pooled partials (all threads) ----
    if (t < 64) {
        float s = 0.f;
        for (int n = t; n < N_; n += 64) s += fabsf(scoreS[n]);
        for (int off = 32; off; off >>= 1) s += __shfl_down(s, off);
        if (t == 0) denomS = s;
    }
    {
        f32x4 p4 = v0 * scoreS[r0] + v1 * scoreS[r0 + 64] + v2 * scoreS[r0 + 128];
        if (has3) p4 += v3 * scoreS[r0 + 192];
        red4[t] = p4;
    }
    __syncthreads();
    if (t < 64) red4[t] = red4[t] + red4[t + 64] + red4[t + 128] + red4[t + 192];
    __syncthreads();
    if (t < 16) {
        float invd = 1.0f / denomS;
        float s = 0.f;
        #pragma unroll
        for (int m = 0; m < 16; m++) s += red4[m * 4 + (t >> 2)][t & 3];
        pooledS[t] = s * invd;
    }
    __syncthreads();

    // ---- h = leaky_relu(pooled @ W1 + b1, 0.2) ----
    if (t < 128) {
        float s = b1[t];
        #pragma unroll
        for (int l = 0; l < 16; l++) s += pooledS[l] * W1[l * H_ + t];
        hS[t] = s > 0.f ? s : 0.2f * s;
    }
    __syncthreads();

    // ---- out0[b, p, d] = h @ W2 + b2 : coalesced scalar W2 (lane-consecutive) ----
    if (t < 96) {
        float s = b2[t];
        for (int j = 0; j < 128; j++) s += hS[j] * W2[j * P_ + t];
        int b = bd >> 6, d = bd & 63;
        out[b * (P_ * D_) + t * D_ + d] = s;
    }
}

extern "C" void kernel_launch(void* const* d_in, const int* in_sizes, int n_in,
                              void* d_out, int out_size, void* d_ws, size_t ws_size,
                              hipStream_t stream) {
    const float* x     = (const float*)d_in[0];
    const float* W_enc = (const float*)d_in[1];
    const float* b_enc = (const float*)d_in[2];
    const float* W1    = (const float*)d_in[3];
    const float* b1    = (const float*)d_in[4];
    const float* W2    = (const float*)d_in[5];
    const float* b2    = (const float*)d_in[6];
    const float* pos   = (const float*)d_in[7];
    float* ws  = (float*)d_ws;
    float* out = (float*)d_out;

    hipLaunchKernelGGL(preK,   dim3(16),    dim3(256), 0, stream, pos, ws);
    hipLaunchKernelGGL(pre2b,  dim3(255),   dim3(128), 0, stream, W_enc, b_enc, pos, ws);
    hipLaunchKernelGGL(mainker, dim3(PAIRS), dim3(256), 0, stream, x, W1, b1, W2, b2, ws, out);
}